// Round 10
// baseline (451.259 us; speedup 1.0000x reference)
//
#include <hip/hip_runtime.h>
#include <stdint.h>

// Problem constants (fixed by setup_inputs; all tensors f32)
#define B_ROWS 4096
#define D_IN   784
#define H_DIM  800
#define D_OUT  10
#define T_SIM  32
#define N_ELEM (B_ROWS * D_IN)   // 3211264
#define NKT    49                // 784 / 16
#define CAP    512               // spiking-list cap/row (mean ~376, sd ~14)

// ---------------------------------------------------------------------------
// Bit-exact JAX threefry2x32 (key = PRNGKey(42) = {0, 42})
// ---------------------------------------------------------------------------
__device__ __forceinline__ void threefry2x32(uint32_t k0, uint32_t k1,
                                             uint32_t& x0, uint32_t& x1) {
  uint32_t ks0 = k0, ks1 = k1, ks2 = k0 ^ k1 ^ 0x1BD11BDAu;
  x0 += ks0; x1 += ks1;
#define TF_RND(r) { x0 += x1; x1 = (x1 << (r)) | (x1 >> (32 - (r))); x1 ^= x0; }
  TF_RND(13) TF_RND(15) TF_RND(26) TF_RND(6)
  x0 += ks1; x1 += ks2 + 1u;
  TF_RND(17) TF_RND(29) TF_RND(16) TF_RND(24)
  x0 += ks2; x1 += ks0 + 2u;
  TF_RND(13) TF_RND(15) TF_RND(26) TF_RND(6)
  x0 += ks0; x1 += ks1 + 3u;
  TF_RND(17) TF_RND(29) TF_RND(16) TF_RND(24)
  x0 += ks1; x1 += ks2 + 4u;
  TF_RND(13) TF_RND(15) TF_RND(26) TF_RND(6)
  x0 += ks2; x1 += ks0 + 5u;
#undef TF_RND
}

// K0: bit-packed x_fixed. Thread = (row, kt): 16 elements -> one u16.
// Same per-element comparison as the R5..R9 passing kernels (exact bits).
// Output layout: xb[panel=row>>6][kt][ml=row&63] -> the GEMM's LDS panel is a
// straight contiguous copy.
__global__ __launch_bounds__(256) void gen_xbits(const float* __restrict__ x,
                                                 uint16_t* __restrict__ xb) {
  int tid = blockIdx.x * 256 + threadIdx.x;    // 784 blocks * 256 = 200704 ✓
  int row = tid / NKT;
  int kt  = tid - row * NKT;
  const float* xp = x + row * D_IN + kt * 16;  // 64B-aligned
  float xv[16];
#pragma unroll
  for (int q = 0; q < 4; ++q) {
    float4 v = *(const float4*)(xp + 4 * q);
    xv[4 * q + 0] = v.x; xv[4 * q + 1] = v.y;
    xv[4 * q + 2] = v.z; xv[4 * q + 3] = v.w;
  }
  uint32_t base = (uint32_t)(row * D_IN + kt * 16);
  uint32_t bits = 0;
#pragma unroll
  for (int j = 0; j < 16; ++j) {
    uint32_t c0 = 0u, c1 = base + j;           // partitionable: counter (0, i)
    threefry2x32(0u, 42u, c0, c1);
    uint32_t b = c0 ^ c1;
    float u = __uint_as_float((b >> 9) | 0x3F800000u) - 1.0f;
    bits |= (u < xv[j]) ? (1u << j) : 0u;
  }
  int panel = row >> 6, ml = row & 63;
  xb[panel * (NKT * 64) + kt * 64 + ml] = (uint16_t)bits;
}

// ---------------------------------------------------------------------------
// K1: cur1 = x_fixed @ W1^T + b1 (exact f32 ascending-k single-accumulator
// chain: fma(a,b,acc) with a in {0,1} == round(acc+b) or identity, identical
// to R9's passing kernel) + fused layer-1 period epilogue.
// A lives as a 6.3 KB bit panel in LDS (1 ds_read_b64 per kt vs 32 b128);
// B double-buffered (1 barrier/kt). 64x64 tile -> 832 blocks (2x waves of R9).
// ---------------------------------------------------------------------------
#define BM 64
#define BN 64
#define BK 16

__global__ __launch_bounds__(256) void gemm_periods(const uint16_t* __restrict__ xb,
                                                    const float* __restrict__ W1,
                                                    const float* __restrict__ b1,
                                                    uint8_t* __restrict__ pb) {
  __shared__ __align__(16) uint16_t Abits[NKT * BM];   // [kt][ml], 6272 B
  __shared__ __align__(16) float Bs[2][BK][BN + 4];    // 2 x 4.3 KB
  const int m0 = blockIdx.y * BM;
  const int n0 = blockIdx.x * BN;
  const int t  = threadIdx.x;        // 0..255
  const int tx = t & 15, ty = t >> 4;
  const int br = t >> 2, bk = (t & 3) * 4;
  const int hB = n0 + br;
  const bool bOK = (hB < H_DIM);
  const float* bptr = W1 + (bOK ? hB : 0) * D_IN + bk;

  // Stage the A-bit panel once (contiguous copy, 392 uint4)
  {
    const uint4* src = (const uint4*)(xb + blockIdx.y * (NKT * BM));
    for (int i = t; i < 392; i += 256) ((uint4*)Abits)[i] = src[i];
  }
  // Stage B tile 0
  {
    float4 b0 = *(const float4*)(bptr);
    if (!bOK) { b0.x = b0.y = b0.z = b0.w = 0.0f; }
    Bs[0][bk + 0][br] = b0.x; Bs[0][bk + 1][br] = b0.y;
    Bs[0][bk + 2][br] = b0.z; Bs[0][bk + 3][br] = b0.w;
  }
  __syncthreads();

  float acc[4][4] = {};
  for (int kt = 0; kt < NKT; ++kt) {          // ascending k, single acc
    const int buf = kt & 1;
    float4 bn;
    if (kt < NKT - 1) {
      bn = *(const float4*)(bptr + (kt + 1) * BK);
      if (!bOK) { bn.x = bn.y = bn.z = bn.w = 0.0f; }
    }
    uint2 av = *(const uint2*)&Abits[kt * BM + ty * 4];  // 4 rows x 16 bits
#pragma unroll
    for (int kk = 0; kk < BK; ++kk) {
      float4 bv = *(const float4*)&Bs[buf][kk][tx * 4];
      float a0 = (float)((av.x >> kk) & 1u);            // exact 0.0/1.0
      float a1 = (float)((av.x >> (16 + kk)) & 1u);
      float a2 = (float)((av.y >> kk) & 1u);
      float a3 = (float)((av.y >> (16 + kk)) & 1u);
      float b[4] = {bv.x, bv.y, bv.z, bv.w};
      float a[4] = {a0, a1, a2, a3};
#pragma unroll
      for (int mi = 0; mi < 4; ++mi)
#pragma unroll
        for (int ni = 0; ni < 4; ++ni)
          acc[mi][ni] = __builtin_fmaf(a[mi], b[ni], acc[mi][ni]);
    }
    if (kt < NKT - 1) {
      Bs[buf ^ 1][bk + 0][br] = bn.x; Bs[buf ^ 1][bk + 1][br] = bn.y;
      Bs[buf ^ 1][bk + 2][br] = bn.z; Bs[buf ^ 1][bk + 3][br] = bn.w;
    }
    __syncthreads();
  }

  // Epilogue: + b1 (f32 add like ref), then exact f32 IF-period loop
  const int hOut = n0 + tx * 4;
  if (hOut < H_DIM) {
    float4 bb = *(const float4*)&b1[hOut];
#pragma unroll
    for (int mi = 0; mi < 4; ++mi) {
      int m = m0 + ty * 4 + mi;
      float c4[4] = {acc[mi][0] + bb.x, acc[mi][1] + bb.y,
                     acc[mi][2] + bb.z, acc[mi][3] + bb.w};
      uint32_t packed = 0;
#pragma unroll
      for (int ni = 0; ni < 4; ++ni) {
        float c = c4[ni];
        float v = 0.0f;
        int p = 0;
#pragma unroll 1
        for (int s = 1; s <= T_SIM; ++s) {
          float h1 = v + c;                   // f32 add, as reference
          if (h1 >= 1.0f) { p = s; break; }
          v = h1;
        }
        packed |= (uint32_t)p << (8 * ni);
      }
      *(uint32_t*)&pb[(size_t)m * H_DIM + hOut] = packed;
    }
  }
}

// ---------------------------------------------------------------------------
// K2: SNN scan; exec stream transported by v_readlane (VALU pipe, per-SIMD)
// instead of per-iteration LDS broadcasts (shared per-CU LDS pipe = R9's
// bottleneck). 2 rows/block, 640 threads: wave=(r, o-pair j), lanes=(half,t).
// Exactness: per (row,t,o) same ascending-h single-accumulator gated fold as
// R9 (passed): skipping never-spiking h is the +0 identity; pad entries have
// mask 0 -> +0.0f; included entries add the identical w values in order.
// ---------------------------------------------------------------------------
__global__ __launch_bounds__(640) void snn_scan(const uint8_t* __restrict__ pb,
                                                const float* __restrict__ W2,
                                                const float* __restrict__ b2,
                                                float* __restrict__ out) {
  __shared__ uint32_t mkS[2][CAP];            // spike masks, 0-padded
  __shared__ uint16_t hidxS[2][CAP];          // ascending h indices
  __shared__ float2   wstS[2][5][CAP];        // w-pair streams (40 KB)
  __shared__ int      lenS[2];
  __shared__ uint32_t mtbl[T_SIM + 1];
  __shared__ float    c2s[2][T_SIM][D_OUT];
  __shared__ float    b2f[D_OUT];
  const int tid  = threadIdx.x;               // 0..639
  const int row0 = blockIdx.x * 2;

  if (tid <= T_SIM) {                         // mask of multiples of p
    uint32_t mk = 0;
    if (tid) for (int s = tid; s <= T_SIM; s += tid) mk |= 1u << (s - 1);
    mtbl[tid] = mk;
  }
  if (tid < D_OUT) b2f[tid] = b2[tid];
  __syncthreads();

  // ---- Build: waves 0-1 ballot-compact the period bytes (ascending h) ----
  if (tid < 128) {
    const int r = tid >> 6, ln = tid & 63;
    const uint64_t lm = (1ull << ln) - 1ull;
    const uint8_t* prow = pb + (size_t)(row0 + r) * H_DIM;
    uint8_t pv[13];
#pragma unroll
    for (int ch = 0; ch < 13; ++ch) {         // independent coalesced loads
      int h = ch * 64 + ln;
      pv[ch] = (h < H_DIM) ? prow[h] : (uint8_t)0;
    }
    int off = 0;
#pragma unroll
    for (int ch = 0; ch < 13; ++ch) {
      bool g = (pv[ch] != 0);
      uint64_t bal = __ballot(g);
      int pos = off + __popcll(bal & lm);
      if (g && pos < CAP) {
        hidxS[r][pos] = (uint16_t)(ch * 64 + ln);
        mkS[r][pos]   = mtbl[pv[ch]];
      }
      off += __popcll(bal);
    }
    if (ln == 0) lenS[r] = off;
  }
  __syncthreads();

  const int L0 = min(lenS[0], CAP), L1 = min(lenS[1], CAP);
  const bool ovf = (lenS[0] > CAP) || (lenS[1] > CAP);
  const int Lpad = (max(L0, L1) + 63) & ~63;  // multiple of 64, <= CAP

  // ---- Pad masks + gather w-streams from L2-hot W2 (all 640 threads) ----
  for (int e = tid; e < 2 * CAP; e += 640) {
    int r = e >= CAP ? 1 : 0, i = e - r * CAP;
    if (i >= (r ? L1 : L0) && i < Lpad) mkS[r][i] = 0u;
  }
#pragma unroll
  for (int r = 0; r < 2; ++r) {
    const int Lr = r ? L1 : L0;
#pragma unroll
    for (int j = 0; j < 5; ++j)
      for (int i = tid; i < Lpad; i += 640) {
        float2 w;
        if (i < Lr) {
          int h = hidxS[r][i];
          w.x = W2[(2 * j) * H_DIM + h];
          w.y = W2[(2 * j + 1) * H_DIM + h];
        } else { w.x = 0.0f; w.y = 0.0f; }
        wstS[r][j][i] = w;
      }
  }
  __syncthreads();

  // ---- Exec: readlane-broadcast stream, pure VALU steady state ----
  {
    const int wv = tid >> 6;                  // 0..9
    const int r = wv & 1, j = wv >> 1;
    const int lane = tid & 63;
    const int t = lane & 31;
    const bool hi = lane >= 32;               // o = 2j (+1 if hi)
    const uint32_t vbit = 1u << t;
    float s = 0.0f;
    if (!ovf) {
      for (int i0 = 0; i0 < Lpad; i0 += 64) {
        uint32_t vmk = mkS[r][i0 + lane];     // coalesced, 1 LDS op / 64 i
        float2 vw = wstS[r][j][i0 + lane];
        uint32_t w0u = __float_as_uint(vw.x);
        uint32_t w1u = __float_as_uint(vw.y);
#pragma unroll
        for (int l = 0; l < 64; ++l) {
          uint32_t smk = __builtin_amdgcn_readlane(vmk, l);
          uint32_t u0  = __builtin_amdgcn_readlane(w0u, l);
          uint32_t u1  = __builtin_amdgcn_readlane(w1u, l);
          float wsel = __uint_as_float(hi ? u1 : u0);
          s += (smk & vbit) ? wsel : 0.0f;    // identical op to ref (+w / +0)
        }
      }
    } else {                                  // overflow fallback: gated scan
      const uint8_t* prow = pb + (size_t)(row0 + r) * H_DIM;
      const int o = 2 * j + (hi ? 1 : 0);
      for (int h = 0; h < H_DIM; ++h) {
        uint32_t mk = mtbl[prow[h]];
        float wv2 = W2[o * H_DIM + h];
        s += (mk & vbit) ? wv2 : 0.0f;
      }
    }
    c2s[r][t][2 * j + (hi ? 1 : 0)] = s;
  }
  __syncthreads();

  // ---- Layer-2 IF scan + spike count (exact f32 ref order) ----
  if (tid < 2 * D_OUT) {
    const int r = tid / D_OUT, o = tid % D_OUT;
    const float bb = b2f[o];
    float v = 0.0f; int cnt = 0;
#pragma unroll
    for (int t = 0; t < T_SIM; ++t) {
      float cur2 = c2s[r][t][o] + bb;         // f32 add of b2, like ref
      float h2 = v + cur2;                    // f32 add
      bool spk = (h2 >= 1.0f);
      cnt += spk ? 1 : 0;
      v = spk ? 0.0f : h2;
    }
    out[(size_t)(row0 + r) * D_OUT + o] = (float)cnt;
  }
}

// ---------------------------------------------------------------------------
extern "C" void kernel_launch(void* const* d_in, const int* in_sizes, int n_in,
                              void* d_out, int out_size, void* d_ws, size_t ws_size,
                              hipStream_t stream) {
  const float* x  = (const float*)d_in[0];
  const float* W1 = (const float*)d_in[1];
  const float* b1 = (const float*)d_in[2];
  const float* W2 = (const float*)d_in[3];
  const float* b2 = (const float*)d_in[4];
  float* outp = (float*)d_out;

  uint16_t* xb = (uint16_t*)d_ws;                   // 200704 u16 (401 KB)
  uint8_t*  pbuf = (uint8_t*)d_ws + 401408;         // B*H bytes (3.28 MB)

  gen_xbits<<<784, 256, 0, stream>>>(x, xb);

  dim3 g1((H_DIM + BN - 1) / BN, B_ROWS / BM);      // 13 x 64 = 832 blocks
  gemm_periods<<<g1, 256, 0, stream>>>(xb, W1, b1, pbuf);

  snn_scan<<<B_ROWS / 2, 640, 0, stream>>>(pbuf, W2, b2, outp);
}

// Round 11
// 315.692 us; speedup vs baseline: 1.4294x; 1.4294x over previous
//
#include <hip/hip_runtime.h>
#include <stdint.h>

// Problem constants (fixed by setup_inputs; all tensors f32)
#define B_ROWS 4096
#define D_IN   784
#define H_DIM  800
#define D_OUT  10
#define T_SIM  32
#define N_ELEM (B_ROWS * D_IN)   // 3211264 = 12544 * 256
#define CAP    512               // spiking-list cap/row (mean ~376, sd ~14)

// ---------------------------------------------------------------------------
// Bit-exact JAX threefry2x32 (key = PRNGKey(42) = {0, 42})
// ---------------------------------------------------------------------------
__device__ __forceinline__ void threefry2x32(uint32_t k0, uint32_t k1,
                                             uint32_t& x0, uint32_t& x1) {
  uint32_t ks0 = k0, ks1 = k1, ks2 = k0 ^ k1 ^ 0x1BD11BDAu;
  x0 += ks0; x1 += ks1;
#define TF_RND(r) { x0 += x1; x1 = (x1 << (r)) | (x1 >> (32 - (r))); x1 ^= x0; }
  TF_RND(13) TF_RND(15) TF_RND(26) TF_RND(6)
  x0 += ks1; x1 += ks2 + 1u;
  TF_RND(17) TF_RND(29) TF_RND(16) TF_RND(24)
  x0 += ks2; x1 += ks0 + 2u;
  TF_RND(13) TF_RND(15) TF_RND(26) TF_RND(6)
  x0 += ks0; x1 += ks1 + 3u;
  TF_RND(17) TF_RND(29) TF_RND(16) TF_RND(24)
  x0 += ks1; x1 += ks2 + 4u;
  TF_RND(13) TF_RND(15) TF_RND(26) TF_RND(6)
  x0 += ks2; x1 += ks0 + 5u;
#undef TF_RND
}

// K0 (R9 verbatim): x_fixed[i] = (u[i] < x[i]) ? 1 : 0.
__global__ __launch_bounds__(256) void gen_xfixed(const float* __restrict__ x,
                                                  float* __restrict__ xf) {
  int i = blockIdx.x * blockDim.x + threadIdx.x;
  if (i >= N_ELEM) return;
  uint32_t c0 = 0u, c1 = (uint32_t)i;
  threefry2x32(0u, 42u, c0, c1);
  uint32_t bits = c0 ^ c1;
  float u = __uint_as_float((bits >> 9) | 0x3F800000u) - 1.0f;
  xf[i] = (u < x[i]) ? 1.0f : 0.0f;
}

// ---------------------------------------------------------------------------
// K1 (R9 verbatim, measured 167 us): fused GEMM + period epilogue.
// Bit-exact f32 ascending-k single-accumulator chain; period loop identical
// f32 add chain to the reference scan. Output: period byte per neuron.
// ---------------------------------------------------------------------------
#define BM 128
#define BN 64
#define BK 16

__global__ __launch_bounds__(256) void gemm_periods(const float* __restrict__ xf,
                                                    const float* __restrict__ W1,
                                                    const float* __restrict__ b1,
                                                    uint8_t* __restrict__ pb) {
  __shared__ __align__(16) float As[BK][BM + 4];
  __shared__ __align__(16) float Bs[BK][BN + 4];
  const int m0 = blockIdx.y * BM;
  const int n0 = blockIdx.x * BN;
  const int t  = threadIdx.x;
  const int tx = t & 15, ty = t >> 4;
  const int ar = t >> 1;
  const int ak = (t & 1) * 8;
  const int br = t >> 2;
  const int bk = (t & 3) * 4;
  const int hB = n0 + br;
  const bool bOK = (hB < H_DIM);
  const float* aptr = xf + (m0 + ar) * D_IN + ak;
  const float* bptr = W1 + (bOK ? hB : 0) * D_IN + bk;

  float4 a0 = *(const float4*)(aptr);
  float4 a1 = *(const float4*)(aptr + 4);
  float4 b0 = *(const float4*)(bptr);
  if (!bOK) { b0.x = b0.y = b0.z = b0.w = 0.0f; }

  float acc[8][4] = {};
  for (int kt = 0; kt < D_IN; kt += BK) {
    As[ak + 0][ar] = a0.x; As[ak + 1][ar] = a0.y;
    As[ak + 2][ar] = a0.z; As[ak + 3][ar] = a0.w;
    As[ak + 4][ar] = a1.x; As[ak + 5][ar] = a1.y;
    As[ak + 6][ar] = a1.z; As[ak + 7][ar] = a1.w;
    Bs[bk + 0][br] = b0.x; Bs[bk + 1][br] = b0.y;
    Bs[bk + 2][br] = b0.z; Bs[bk + 3][br] = b0.w;
    __syncthreads();
    if (kt + BK < D_IN) {
      a0 = *(const float4*)(aptr + kt + BK);
      a1 = *(const float4*)(aptr + kt + BK + 4);
      b0 = *(const float4*)(bptr + kt + BK);
      if (!bOK) { b0.x = b0.y = b0.z = b0.w = 0.0f; }
    }
#pragma unroll
    for (int kk = 0; kk < BK; kk++) {
      float4 av0 = *(const float4*)&As[kk][ty * 8];
      float4 av1 = *(const float4*)&As[kk][ty * 8 + 4];
      float4 bv  = *(const float4*)&Bs[kk][tx * 4];
      float a[8] = {av0.x, av0.y, av0.z, av0.w, av1.x, av1.y, av1.z, av1.w};
      float b[4] = {bv.x, bv.y, bv.z, bv.w};
#pragma unroll
      for (int mi = 0; mi < 8; mi++)
#pragma unroll
        for (int ni = 0; ni < 4; ni++)
          acc[mi][ni] = __builtin_fmaf(a[mi], b[ni], acc[mi][ni]);
    }
    __syncthreads();
  }
  const int hOut = n0 + tx * 4;
  if (hOut < H_DIM) {
    float4 bb = *(const float4*)&b1[hOut];
#pragma unroll
    for (int mi = 0; mi < 8; mi++) {
      int m = m0 + ty * 8 + mi;
      float c4[4] = {acc[mi][0] + bb.x, acc[mi][1] + bb.y,
                     acc[mi][2] + bb.z, acc[mi][3] + bb.w};
      uint32_t packed = 0;
#pragma unroll
      for (int ni = 0; ni < 4; ni++) {
        float c = c4[ni];
        float v = 0.0f;
        int p = 0;
#pragma unroll 1
        for (int s = 1; s <= T_SIM; s++) {
          float h1 = v + c;                   // f32 add, as reference
          if (h1 >= 1.0f) { p = s; break; }
          v = h1;
        }
        packed |= (uint32_t)p << (8 * ni);
      }
      *(uint32_t*)&pb[(size_t)m * H_DIM + hOut] = packed;
    }
  }
}

// ---------------------------------------------------------------------------
// K2: SNN scan; exec at 1 LDS op + 3 VALU per entry.
// w-stream interleaved by entry-pair: wst[((r*5+j)*(CAP/2)+i2)*4 + hi*2 + q]
// so one 2-distinct ds_read_b64 delivers 2 entries' w per lane; masks read
// as broadcast b64 pairs. Gate: fmaf(cvt(bit), w, s) — fmaf(1,w,s) =
// round(s+w), fmaf(0,w,s) = s: identical rounding chain to the reference's
// ascending-h gated fold (passing since R5). Pad entries: mask=0 AND w=0.
// ---------------------------------------------------------------------------
__global__ __launch_bounds__(640) void snn_scan(const uint8_t* __restrict__ pb,
                                                const float* __restrict__ W2,
                                                const float* __restrict__ b2,
                                                float* __restrict__ out) {
  __shared__ __align__(8) uint32_t mkS[2][CAP];       // 4 KB, 0-padded
  __shared__ uint16_t hidxS[2][CAP];                  // 2 KB
  __shared__ __align__(16) float wst[2 * 5 * (CAP / 2) * 4];  // 40 KB
  __shared__ int      lenS[2];
  __shared__ uint32_t mtbl[T_SIM + 1];
  __shared__ float    c2s[2][T_SIM][D_OUT];
  __shared__ float    b2f[D_OUT];
  const int tid  = threadIdx.x;               // 0..639
  const int row0 = blockIdx.x * 2;

  if (tid <= T_SIM) {                         // mask of multiples of p
    uint32_t mk = 0;
    if (tid) for (int s = tid; s <= T_SIM; s += tid) mk |= 1u << (s - 1);
    mtbl[tid] = mk;
  }
  if (tid < D_OUT) b2f[tid] = b2[tid];
  __syncthreads();

  // ---- Build: waves 0-1 ballot-compact the period bytes (ascending h) ----
  if (tid < 128) {
    const int r = tid >> 6, ln = tid & 63;
    const uint64_t lm = (1ull << ln) - 1ull;
    const uint8_t* prow = pb + (size_t)(row0 + r) * H_DIM;
    uint8_t pv[13];
#pragma unroll
    for (int ch = 0; ch < 13; ++ch) {
      int h = ch * 64 + ln;
      pv[ch] = (h < H_DIM) ? prow[h] : (uint8_t)0;
    }
    int off = 0;
#pragma unroll
    for (int ch = 0; ch < 13; ++ch) {
      bool g = (pv[ch] != 0);
      uint64_t bal = __ballot(g);
      int pos = off + __popcll(bal & lm);
      if (g && pos < CAP) {
        hidxS[r][pos] = (uint16_t)(ch * 64 + ln);
        mkS[r][pos]   = mtbl[pv[ch]];
      }
      off += __popcll(bal);
    }
    if (ln == 0) lenS[r] = off;
  }
  __syncthreads();

  const int L0 = min(lenS[0], CAP), L1 = min(lenS[1], CAP);
  const bool ovf = (lenS[0] > CAP) || (lenS[1] > CAP);
  const int Lpad = (max(L0, L1) + 63) & ~63;  // multiple of 64, <= CAP

  // ---- Pad mask stream ----
  for (int e = tid; e < 2 * CAP; e += 640) {
    int r = e >= CAP ? 1 : 0, i = e - r * CAP;
    if (i >= (r ? L1 : L0)) mkS[r][i] = 0u;
  }
  __syncthreads();                            // hidx/len visible to all

  // ---- Gather w-streams (all 640 threads, L2-hot W2) ----
  // e indexes (r, j, i2, hi); each thread writes one float2 (entries 2*i2,+1)
  {
    const int npairs = Lpad >> 1;             // i2 count
    for (int e = tid; e < 10 * npairs * 2; e += 640) {
      int tmpe = e;
      int hi = tmpe & 1; tmpe >>= 1;
      int i2 = tmpe % npairs; tmpe /= npairs;
      int j = tmpe % 5;  int r = tmpe / 5;
      const int o = 2 * j + hi;
      const int Lr = r ? L1 : L0;
      float2 w;
      int i0 = 2 * i2;
      w.x = (i0     < Lr) ? W2[o * H_DIM + hidxS[r][i0]]     : 0.0f;
      w.y = (i0 + 1 < Lr) ? W2[o * H_DIM + hidxS[r][i0 + 1]] : 0.0f;
      *(float2*)&wst[((r * 5 + j) * (CAP / 2) + i2) * 4 + hi * 2] = w;
    }
  }
  __syncthreads();

  // ---- Exec: wave (r,j), lanes (t,hi); 1 LDS op + 3 VALU per entry ----
  {
    const int wv = tid >> 6;                  // 0..9
    const int r = wv & 1, j = wv >> 1;
    const int lane = tid & 63;
    const int t = lane & 31;
    const int hi = lane >> 5;
    float s = 0.0f;
    if (!ovf) {
      const uint32_t* mbase = mkS[r];
      const float* wbase = &wst[(r * 5 + j) * (CAP / 2) * 4 + hi * 2];
      const int npairs = Lpad >> 1;
#pragma unroll 4
      for (int i2 = 0; i2 < npairs; ++i2) {
        uint2 mk2 = *(const uint2*)&mbase[2 * i2];          // broadcast b64
        float2 w2 = *(const float2*)(wbase + i2 * 4);       // 2-distinct b64
        float g0 = (float)((mk2.x >> t) & 1u);
        s = __builtin_fmaf(g0, w2.x, s);      // == ref step: +w or identity
        float g1 = (float)((mk2.y >> t) & 1u);
        s = __builtin_fmaf(g1, w2.y, s);
      }
    } else {                                  // overflow fallback: gated scan
      const uint8_t* prow = pb + (size_t)(row0 + r) * H_DIM;
      const int o = 2 * j + hi;
      const uint32_t vbit = 1u << t;
      for (int h = 0; h < H_DIM; ++h) {
        uint32_t mk = mtbl[prow[h]];
        float w = W2[o * H_DIM + h];
        s += (mk & vbit) ? w : 0.0f;
      }
    }
    c2s[r][t][2 * j + hi] = s;
  }
  __syncthreads();

  // ---- Layer-2 IF scan + spike count (exact f32 ref order) ----
  if (tid < 2 * D_OUT) {
    const int r = tid / D_OUT, o = tid % D_OUT;
    const float bb = b2f[o];
    float v = 0.0f; int cnt = 0;
#pragma unroll
    for (int t = 0; t < T_SIM; ++t) {
      float cur2 = c2s[r][t][o] + bb;         // f32 add of b2, like ref
      float h2 = v + cur2;                    // f32 add
      bool spk = (h2 >= 1.0f);
      cnt += spk ? 1 : 0;
      v = spk ? 0.0f : h2;
    }
    out[(size_t)(row0 + r) * D_OUT + o] = (float)cnt;
  }
}

// ---------------------------------------------------------------------------
extern "C" void kernel_launch(void* const* d_in, const int* in_sizes, int n_in,
                              void* d_out, int out_size, void* d_ws, size_t ws_size,
                              hipStream_t stream) {
  const float* x  = (const float*)d_in[0];
  const float* W1 = (const float*)d_in[1];
  const float* b1 = (const float*)d_in[2];
  const float* W2 = (const float*)d_in[3];
  const float* b2 = (const float*)d_in[4];
  float* outp = (float*)d_out;

  float*   xf = (float*)d_ws;                       // N_ELEM f32 (12.85 MB)
  uint8_t* pbuf = (uint8_t*)(xf + N_ELEM);          // B*H bytes  (3.28 MB)

  gen_xfixed<<<N_ELEM / 256, 256, 0, stream>>>(x, xf);

  dim3 g1((H_DIM + BN - 1) / BN, B_ROWS / BM);      // 13 x 32
  gemm_periods<<<g1, 256, 0, stream>>>(xf, W1, b1, pbuf);

  snn_scan<<<B_ROWS / 2, 640, 0, stream>>>(pbuf, W2, b2, outp);
}